// Round 5
// baseline (1676.470 us; speedup 1.0000x reference)
//
#include <hip/hip_runtime.h>
#include <hip/hip_bf16.h>

// Problem constants (from reference)
#define N_NODES 50000
#define N_REL   8
#define DIM     128      // IN_DIM == HID == 128
#define N_EDGES 800000
#define N_TRIP  100000
#define NSEG    (N_NODES * N_REL)   // 400000
#define SCAN_CHUNK 1024
#define N_SCAN_BLOCKS ((NSEG + SCAN_CHUNK - 1) / SCAN_CHUNK)  // 391

typedef __attribute__((ext_vector_type(8))) short bf16x8;
typedef __attribute__((ext_vector_type(4))) float f32x4;

static __device__ __forceinline__ unsigned short f2b(float f) {
    __hip_bfloat16 h = __float2bfloat16(f);
    return *reinterpret_cast<unsigned short*>(&h);
}
static __device__ __forceinline__ float b2f(unsigned short u) {
    __hip_bfloat16 h;
    *reinterpret_cast<unsigned short*>(&h) = u;
    return __bfloat162float(h);
}

// ---------------------------------------------------------------------------
// histogram over segments seg = rel * N_NODES + dst   (NOTE: rel-major!)
__global__ void hist_kernel(const int* __restrict__ edge_index,
                            const int* __restrict__ edge_type,
                            int* __restrict__ cnt) {
    int e = blockIdx.x * blockDim.x + threadIdx.x;
    if (e >= N_EDGES) return;
    int dst = edge_index[N_EDGES + e];
    int r = edge_type[e];
    atomicAdd(&cnt[r * N_NODES + dst], 1);
}

// ---------------------------------------------------------------------------
__global__ void scan1_kernel(const int* __restrict__ cnt,
                             int* __restrict__ offsets,
                             int* __restrict__ blocksums) {
    __shared__ int sh[256];
    int t = threadIdx.x;
    int base = blockIdx.x * SCAN_CHUNK + t * 4;
    int v[4];
    int s = 0;
    #pragma unroll
    for (int j = 0; j < 4; ++j) {
        v[j] = (base + j < NSEG) ? cnt[base + j] : 0;
        s += v[j];
    }
    sh[t] = s;
    __syncthreads();
    #pragma unroll
    for (int off = 1; off < 256; off <<= 1) {
        int x = (t >= off) ? sh[t - off] : 0;
        __syncthreads();
        sh[t] += x;
        __syncthreads();
    }
    int ex = sh[t] - s;
    #pragma unroll
    for (int j = 0; j < 4; ++j) {
        if (base + j < NSEG) offsets[base + j] = ex;
        ex += v[j];
    }
    if (t == 255) blocksums[blockIdx.x] = sh[255];
}

__global__ void scan2_kernel(int* __restrict__ blocksums) {
    __shared__ int sh[512];
    int t = threadIdx.x;
    int orig = (t < N_SCAN_BLOCKS) ? blocksums[t] : 0;
    sh[t] = orig;
    __syncthreads();
    #pragma unroll
    for (int off = 1; off < 512; off <<= 1) {
        int x = (t >= off) ? sh[t - off] : 0;
        __syncthreads();
        sh[t] += x;
        __syncthreads();
    }
    if (t < N_SCAN_BLOCKS) blocksums[t] = sh[t] - orig;
}

__global__ void scan3_kernel(int* __restrict__ offsets,
                             const int* __restrict__ blocksums,
                             int* __restrict__ cursor) {
    int t = threadIdx.x;
    int boff = blocksums[blockIdx.x];
    int base = blockIdx.x * SCAN_CHUNK + t * 4;
    #pragma unroll
    for (int j = 0; j < 4; ++j) {
        int i = base + j;
        if (i < NSEG) {
            int v = offsets[i] + boff;
            offsets[i] = v;
            cursor[i] = v;
        }
    }
    if (blockIdx.x == 0 && t == 0) offsets[NSEG] = N_EDGES;
}

// ---------------------------------------------------------------------------
// reorder: sorted_pack[pos] = src | (dst<<16)   (both < 65536)
__global__ void reorder_kernel(const int* __restrict__ edge_index,
                               const int* __restrict__ edge_type,
                               int* __restrict__ cursor,
                               unsigned int* __restrict__ sorted_pack) {
    int e = blockIdx.x * blockDim.x + threadIdx.x;
    if (e >= N_EDGES) return;
    int src = edge_index[e];
    int dst = edge_index[N_EDGES + e];
    int r = edge_type[e];
    int seg = r * N_NODES + dst;
    int pos = atomicAdd(&cursor[seg], 1);
    sorted_pack[pos] = (unsigned int)src | ((unsigned int)dst << 16);
}

// ---------------------------------------------------------------------------
// cvt_emb: fp32 -> bf16, 2 elems/thread (packed)
__global__ void cvt_emb_kernel(const float* __restrict__ src,
                               unsigned short* __restrict__ dst) {
    int i = blockIdx.x * blockDim.x + threadIdx.x;   // pair index
    const int npair = N_NODES * DIM / 2;
    if (i >= npair) return;
    float2 v = ((const float2*)src)[i];
    unsigned int p = (unsigned int)f2b(v.x) | ((unsigned int)f2b(v.y) << 16);
    ((unsigned int*)dst)[i] = p;
}

// ---------------------------------------------------------------------------
// cvt_w: build Wt[n][k] (bf16, n-major, k=0..1151) from root(128x128) and
// W(1024x128), both fp32 row-major [k][n].
__global__ void cvt_w_kernel(const float* __restrict__ root,
                             const float* __restrict__ W,
                             unsigned short* __restrict__ Wt) {
    int n = blockIdx.x;          // 0..127
    for (int k = threadIdx.x; k < 1152; k += blockDim.x) {
        float v = (k < 128) ? root[k * 128 + n] : W[(size_t)(k - 128) * 128 + n];
        Wt[(size_t)n * 1152 + k] = f2b(v);
    }
}

// ---------------------------------------------------------------------------
// fused layer: hout = bf16(relu(bias + h@root + sum_r mean_r(h)@W_r))
// Block owns 64 dst rows. 9 phases (root + 8 relations), K=128 each.
// Relation phases build the 64x128 mean tile in LDS (fp32 ds_add from
// gathered h rows), then MFMA against W_r. mean never touches HBM.
__global__ __launch_bounds__(256) void fused_layer(
        const unsigned short* __restrict__ hb,       // N x 128 bf16
        const unsigned short* __restrict__ Wt,       // 128 x 1152 bf16 n-major
        const float* __restrict__ bias,              // 128
        const int* __restrict__ offsets,             // NSEG+1 (rel-major segs)
        const unsigned int* __restrict__ sorted_pack,// N_EDGES
        unsigned short* __restrict__ hout) {         // N x 128 bf16
    __shared__ float Af[64][132];           // mean accum, +4 pad (33792 B)
    __shared__ unsigned short Bs[128][136]; // W tile, +8 pad (34816 B)
    __shared__ float invs[64];

    int tid = threadIdx.x;
    int wave = tid >> 6, lane = tid & 63;
    int wm = wave & 1, wn = wave >> 1;
    int quad = lane >> 4, l16 = lane & 15;
    int sub = lane >> 4;                    // edge slot within wave
    int row0 = blockIdx.x * 64;
    int nval = N_NODES - row0; if (nval > 64) nval = 64;

    f32x4 acc[2][4];
    #pragma unroll
    for (int i = 0; i < 2; ++i)
        #pragma unroll
        for (int j = 0; j < 4; ++j) acc[i][j] = (f32x4){0.f, 0.f, 0.f, 0.f};

    for (int p = 0; p < 9; ++p) {
        int kb = p * 128;
        __syncthreads();   // previous phase's MFMA done with Af/Bs/invs

        // ---- stage B tile (128 n-rows x 128 k) from Wt ----
        // 2 threads per row, 64 columns (8 x bf16x8 stores) each  [BUGFIX: q<8]
        {
            int n = tid >> 1, half = tid & 1;
            const unsigned short* gp = Wt + (size_t)n * 1152 + kb + half * 64;
            #pragma unroll
            for (int q = 0; q < 8; ++q)
                *(bf16x8*)&Bs[n][half * 64 + q * 8] = *(const bf16x8*)(gp + q * 8);
        }

        int eb = 0, ee = 0;
        if (p > 0) {
            int r = p - 1;
            int s0 = r * N_NODES + row0;
            eb = offsets[s0];
            ee = offsets[s0 + nval];
            // zero Af (flat float4)
            float4 z = make_float4(0.f, 0.f, 0.f, 0.f);
            float4* az = (float4*)&Af[0][0];
            #pragma unroll
            for (int i = 0; i < 9; ++i) {
                int idx = tid + i * 256;
                if (idx < 64 * 132 / 4) az[idx] = z;
            }
            if (tid < 64) {
                float iv = 0.f;
                if (tid < nval) {
                    int c = offsets[s0 + tid + 1] - offsets[s0 + tid];
                    iv = (c > 0) ? 1.0f / (float)c : 0.f;
                }
                invs[tid] = iv;
            }
            __syncthreads();   // Af zeros visible before atomics
            // ---- edge gather + LDS fp32 accumulate ----
            // wave w takes 4 edges per iter (16 lanes per edge row)
            for (int e0 = eb + wave * 4; e0 < ee; e0 += 16) {
                int e = e0 + sub;
                if (e < ee) {
                    unsigned int pk = sorted_pack[e];
                    int src = (int)(pk & 0xffffu);
                    int dstl = (int)(pk >> 16) - row0;
                    uint4 v = ((const uint4*)(hb + (size_t)src * DIM))[l16];
                    float* ap = &Af[dstl][l16 * 8];
                    atomicAdd(ap + 0, b2f((unsigned short)(v.x & 0xffff)));
                    atomicAdd(ap + 1, b2f((unsigned short)(v.x >> 16)));
                    atomicAdd(ap + 2, b2f((unsigned short)(v.y & 0xffff)));
                    atomicAdd(ap + 3, b2f((unsigned short)(v.y >> 16)));
                    atomicAdd(ap + 4, b2f((unsigned short)(v.z & 0xffff)));
                    atomicAdd(ap + 5, b2f((unsigned short)(v.z >> 16)));
                    atomicAdd(ap + 6, b2f((unsigned short)(v.w & 0xffff)));
                    atomicAdd(ap + 7, b2f((unsigned short)(v.w >> 16)));
                }
            }
        }
        __syncthreads();   // Af / Bs ready

        // ---- MFMA: 4 k-steps of 32 ----
        #pragma unroll
        for (int kk = 0; kk < 4; ++kk) {
            bf16x8 afr[2], bfr[4];
            #pragma unroll
            for (int i = 0; i < 2; ++i) {
                int arow = wm * 32 + i * 16 + l16;
                if (p == 0) {
                    int grow = row0 + arow;
                    if (grow >= N_NODES) grow = N_NODES - 1;
                    afr[i] = *(const bf16x8*)(hb + (size_t)grow * DIM + kk * 32 + quad * 8);
                } else {
                    float iv = invs[arow];
                    f32x4 x0 = *(const f32x4*)&Af[arow][kk * 32 + quad * 8];
                    f32x4 x1 = *(const f32x4*)&Af[arow][kk * 32 + quad * 8 + 4];
                    bf16x8 fr;
                    fr[0] = (short)f2b(x0.x * iv);
                    fr[1] = (short)f2b(x0.y * iv);
                    fr[2] = (short)f2b(x0.z * iv);
                    fr[3] = (short)f2b(x0.w * iv);
                    fr[4] = (short)f2b(x1.x * iv);
                    fr[5] = (short)f2b(x1.y * iv);
                    fr[6] = (short)f2b(x1.z * iv);
                    fr[7] = (short)f2b(x1.w * iv);
                    afr[i] = fr;
                }
            }
            #pragma unroll
            for (int j = 0; j < 4; ++j)
                bfr[j] = *(const bf16x8*)&Bs[wn * 64 + j * 16 + l16][kk * 32 + quad * 8];
            #pragma unroll
            for (int i = 0; i < 2; ++i)
                #pragma unroll
                for (int j = 0; j < 4; ++j)
                    acc[i][j] = __builtin_amdgcn_mfma_f32_16x16x32_bf16(
                        afr[i], bfr[j], acc[i][j], 0, 0, 0);
        }
    }

    // epilogue: C/D layout col=lane&15, row=(lane>>4)*4+reg
    #pragma unroll
    for (int i = 0; i < 2; ++i) {
        int gr0 = row0 + wm * 32 + i * 16 + quad * 4;
        #pragma unroll
        for (int j = 0; j < 4; ++j) {
            int gc = wn * 64 + j * 16 + l16;
            float bv = bias[gc];
            #pragma unroll
            for (int r = 0; r < 4; ++r) {
                int grow = gr0 + r;
                if (grow < N_NODES) {
                    float v = acc[i][j][r] + bv;
                    hout[(size_t)grow * 128 + gc] = f2b(fmaxf(v, 0.f));
                }
            }
        }
    }
}

// ---------------------------------------------------------------------------
// score: out[t] = sum_d h[head,d]*rel_emb[rel,d]*h[tail,d]  (h in bf16)
__global__ void score_kernel(const unsigned short* __restrict__ hb,
                             const float* __restrict__ rel_emb,
                             const int* __restrict__ head,
                             const int* __restrict__ rel,
                             const int* __restrict__ tail,
                             float* __restrict__ out) {
    int t = blockIdx.x * 4 + (threadIdx.x >> 6);
    if (t >= N_TRIP) return;
    int lane = threadIdx.x & 63;
    unsigned int ph = ((const unsigned int*)(hb + (size_t)head[t] * DIM))[lane];
    unsigned int pt = ((const unsigned int*)(hb + (size_t)tail[t] * DIM))[lane];
    float2 rr = ((const float2*)(rel_emb + (size_t)rel[t] * DIM))[lane];
    float s = b2f((unsigned short)(ph & 0xffff)) * rr.x * b2f((unsigned short)(pt & 0xffff))
            + b2f((unsigned short)(ph >> 16))   * rr.y * b2f((unsigned short)(pt >> 16));
    #pragma unroll
    for (int off = 32; off; off >>= 1) s += __shfl_xor(s, off, 64);
    if (lane == 0) out[t] = s;
}

// ---------------------------------------------------------------------------
extern "C" void kernel_launch(void* const* d_in, const int* in_sizes, int n_in,
                              void* d_out, int out_size, void* d_ws, size_t ws_size,
                              hipStream_t stream) {
    const float* emb     = (const float*)d_in[0];
    const float* W0      = (const float*)d_in[1];
    const float* root0   = (const float*)d_in[2];
    const float* b0      = (const float*)d_in[3];
    const float* W1      = (const float*)d_in[4];
    const float* root1   = (const float*)d_in[5];
    const float* b1      = (const float*)d_in[6];
    const float* rel_emb = (const float*)d_in[7];
    const int* edge_index = (const int*)d_in[8];
    const int* edge_type  = (const int*)d_in[9];
    const int* head_idx   = (const int*)d_in[10];
    const int* rel_idx    = (const int*)d_in[11];
    const int* tail_idx   = (const int*)d_in[12];
    float* out = (float*)d_out;

    // workspace layout (~47 MB, all disjoint):
    char* p = (char*)d_ws;
    size_t hb_bytes = (size_t)N_NODES * DIM * sizeof(unsigned short);   // 12.8 MB
    size_t wt_bytes = (size_t)128 * 1152 * sizeof(unsigned short);      // 288 KB
    unsigned short* embb = (unsigned short*)p; p += hb_bytes;
    unsigned short* h1b  = (unsigned short*)p; p += hb_bytes;
    unsigned short* h2b  = (unsigned short*)p; p += hb_bytes;
    unsigned short* Wt0  = (unsigned short*)p; p += wt_bytes;
    unsigned short* Wt1  = (unsigned short*)p; p += wt_bytes;
    int* offsets = (int*)p;          p += (size_t)(NSEG + 1) * sizeof(int);
    unsigned int* sorted_pack = (unsigned int*)p; p += (size_t)N_EDGES * sizeof(unsigned int);
    int* cnt     = (int*)p;          p += (size_t)NSEG * sizeof(int);
    int* cursor  = (int*)p;          p += (size_t)NSEG * sizeof(int);
    int* blocksums = (int*)p;
    (void)ws_size; (void)in_sizes; (void)n_in; (void)out_size;

    dim3 blk256(256);

    // ---- sort edges by (rel, dst) segment (layer-invariant) ----
    hipMemsetAsync(cnt, 0, (size_t)NSEG * sizeof(int), stream);
    hist_kernel<<<(N_EDGES + 255) / 256, blk256, 0, stream>>>(edge_index, edge_type, cnt);
    scan1_kernel<<<N_SCAN_BLOCKS, blk256, 0, stream>>>(cnt, offsets, blocksums);
    scan2_kernel<<<1, 512, 0, stream>>>(blocksums);
    scan3_kernel<<<N_SCAN_BLOCKS, blk256, 0, stream>>>(offsets, blocksums, cursor);
    reorder_kernel<<<(N_EDGES + 255) / 256, blk256, 0, stream>>>(edge_index, edge_type,
                                                                 cursor, sorted_pack);

    // ---- precision conversions ----
    cvt_emb_kernel<<<(N_NODES * DIM / 2 + 255) / 256, blk256, 0, stream>>>(emb, embb);
    cvt_w_kernel<<<128, blk256, 0, stream>>>(root0, W0, Wt0);
    cvt_w_kernel<<<128, blk256, 0, stream>>>(root1, W1, Wt1);

    int gemm_grid = (N_NODES + 63) / 64;           // 782

    // ---- fused layers ----
    fused_layer<<<gemm_grid, blk256, 0, stream>>>(embb, Wt0, b0, offsets, sorted_pack, h1b);
    fused_layer<<<gemm_grid, blk256, 0, stream>>>(h1b, Wt1, b1, offsets, sorted_pack, h2b);

    // ---- score ----
    score_kernel<<<(N_TRIP + 3) / 4, blk256, 0, stream>>>(h2b, rel_emb, head_idx, rel_idx,
                                                          tail_idx, out);
}

// Round 6
// 530.867 us; speedup vs baseline: 3.1580x; 3.1580x over previous
//
#include <hip/hip_runtime.h>
#include <hip/hip_bf16.h>

// Problem constants (from reference)
#define N_NODES 50000
#define N_REL   8
#define DIM     128      // IN_DIM == HID == 128
#define N_EDGES 800000
#define N_TRIP  100000
#define NSEG    (N_NODES * N_REL)   // 400000
#define SCAN_CHUNK 1024
#define N_SCAN_BLOCKS ((NSEG + SCAN_CHUNK - 1) / SCAN_CHUNK)  // 391

typedef __attribute__((ext_vector_type(8))) short bf16x8;
typedef __attribute__((ext_vector_type(4))) float f32x4;

static __device__ __forceinline__ unsigned short f2b(float f) {
    __hip_bfloat16 h = __float2bfloat16(f);
    return *reinterpret_cast<unsigned short*>(&h);
}
static __device__ __forceinline__ float blo(unsigned int u) {
    return __uint_as_float(u << 16);
}
static __device__ __forceinline__ float bhi(unsigned int u) {
    return __uint_as_float(u & 0xffff0000u);
}

// ---------------------------------------------------------------------------
// histogram over segments seg = rel * N_NODES + dst   (rel-major)
__global__ void hist_kernel(const int* __restrict__ edge_index,
                            const int* __restrict__ edge_type,
                            int* __restrict__ cnt) {
    int e = blockIdx.x * blockDim.x + threadIdx.x;
    if (e >= N_EDGES) return;
    int dst = edge_index[N_EDGES + e];
    int r = edge_type[e];
    atomicAdd(&cnt[r * N_NODES + dst], 1);
}

// ---------------------------------------------------------------------------
__global__ void scan1_kernel(const int* __restrict__ cnt,
                             int* __restrict__ offsets,
                             int* __restrict__ blocksums) {
    __shared__ int sh[256];
    int t = threadIdx.x;
    int base = blockIdx.x * SCAN_CHUNK + t * 4;
    int v[4];
    int s = 0;
    #pragma unroll
    for (int j = 0; j < 4; ++j) {
        v[j] = (base + j < NSEG) ? cnt[base + j] : 0;
        s += v[j];
    }
    sh[t] = s;
    __syncthreads();
    #pragma unroll
    for (int off = 1; off < 256; off <<= 1) {
        int x = (t >= off) ? sh[t - off] : 0;
        __syncthreads();
        sh[t] += x;
        __syncthreads();
    }
    int ex = sh[t] - s;
    #pragma unroll
    for (int j = 0; j < 4; ++j) {
        if (base + j < NSEG) offsets[base + j] = ex;
        ex += v[j];
    }
    if (t == 255) blocksums[blockIdx.x] = sh[255];
}

__global__ void scan2_kernel(int* __restrict__ blocksums) {
    __shared__ int sh[512];
    int t = threadIdx.x;
    int orig = (t < N_SCAN_BLOCKS) ? blocksums[t] : 0;
    sh[t] = orig;
    __syncthreads();
    #pragma unroll
    for (int off = 1; off < 512; off <<= 1) {
        int x = (t >= off) ? sh[t - off] : 0;
        __syncthreads();
        sh[t] += x;
        __syncthreads();
    }
    if (t < N_SCAN_BLOCKS) blocksums[t] = sh[t] - orig;
}

__global__ void scan3_kernel(int* __restrict__ offsets,
                             const int* __restrict__ blocksums,
                             int* __restrict__ cursor) {
    int t = threadIdx.x;
    int boff = blocksums[blockIdx.x];
    int base = blockIdx.x * SCAN_CHUNK + t * 4;
    #pragma unroll
    for (int j = 0; j < 4; ++j) {
        int i = base + j;
        if (i < NSEG) {
            int v = offsets[i] + boff;
            offsets[i] = v;
            cursor[i] = v;
        }
    }
    if (blockIdx.x == 0 && t == 0) offsets[NSEG] = N_EDGES;
}

// ---------------------------------------------------------------------------
// reorder: sorted_src[pos] = src  (dst implied by segment)
__global__ void reorder_kernel(const int* __restrict__ edge_index,
                               const int* __restrict__ edge_type,
                               int* __restrict__ cursor,
                               int* __restrict__ sorted_src) {
    int e = blockIdx.x * blockDim.x + threadIdx.x;
    if (e >= N_EDGES) return;
    int src = edge_index[e];
    int dst = edge_index[N_EDGES + e];
    int r = edge_type[e];
    int seg = r * N_NODES + dst;
    int pos = atomicAdd(&cursor[seg], 1);
    sorted_src[pos] = src;
}

// ---------------------------------------------------------------------------
// cvt_emb: fp32 -> bf16, 2 elems/thread (packed)
__global__ void cvt_emb_kernel(const float* __restrict__ src,
                               unsigned short* __restrict__ dst) {
    int i = blockIdx.x * blockDim.x + threadIdx.x;   // pair index
    const int npair = N_NODES * DIM / 2;
    if (i >= npair) return;
    float2 v = ((const float2*)src)[i];
    unsigned int p = (unsigned int)f2b(v.x) | ((unsigned int)f2b(v.y) << 16);
    ((unsigned int*)dst)[i] = p;
}

// ---------------------------------------------------------------------------
// cvt_w: build Wt[n][k] (bf16, n-major, k=0..1151) from root(128x128) and
// W(1024x128), both fp32 row-major [k][n].
__global__ void cvt_w_kernel(const float* __restrict__ root,
                             const float* __restrict__ W,
                             unsigned short* __restrict__ Wt) {
    int n = blockIdx.x;          // 0..127
    for (int k = threadIdx.x; k < 1152; k += blockDim.x) {
        float v = (k < 128) ? root[k * 128 + n] : W[(size_t)(k - 128) * 128 + n];
        Wt[(size_t)n * 1152 + k] = f2b(v);
    }
}

// ---------------------------------------------------------------------------
// fused layer: hout = bf16(relu(bias + h@root + sum_r mean_r(h)@W_r))
// Block owns 64 dst rows; 9 phases (root + 8 relations), K=128 each.
// Relation phase: each 8-lane group EXCLUSIVELY owns dst rows d0 and d0+32 —
// walks the row's contiguous edge range, gathers h[src] (2 x uint4 / lane),
// accumulates 16 fp32 in registers, writes the bf16 mean row to LDS once.
// No atomics anywhere. mean never touches HBM.
__global__ __launch_bounds__(256) void fused_layer(
        const unsigned short* __restrict__ hb,       // N x 128 bf16
        const unsigned short* __restrict__ Wt,       // 128 x 1152 bf16 n-major
        const float* __restrict__ bias,              // 128
        const int* __restrict__ offsets,             // NSEG+1 (rel-major segs)
        const int* __restrict__ sorted_src,          // N_EDGES
        unsigned short* __restrict__ hout) {         // N x 128 bf16
    __shared__ unsigned short Af[64][136];   // bf16 mean tile (+8 pad) 17408 B
    __shared__ unsigned short Bs[128][136];  // W tile (+8 pad)         34816 B

    int tid = threadIdx.x;
    int wave = tid >> 6, lane = tid & 63;
    int wm = wave & 1, wn = wave >> 1;
    int quad = lane >> 4, l16 = lane & 15;
    int d0 = tid >> 3;                 // group id 0..31 (8 lanes/group)
    int g = tid & 7;                   // lane within group
    int row0 = blockIdx.x * 64;
    int nval = N_NODES - row0; if (nval > 64) nval = 64;

    f32x4 acc[2][4];
    #pragma unroll
    for (int i = 0; i < 2; ++i)
        #pragma unroll
        for (int j = 0; j < 4; ++j) acc[i][j] = (f32x4){0.f, 0.f, 0.f, 0.f};

    for (int p = 0; p < 9; ++p) {
        __syncthreads();   // previous phase's MFMA done with Af/Bs

        // ---- stage B tile (128 n-rows x 128 k) from Wt ----
        {
            int n = tid >> 1, half = tid & 1;
            const unsigned short* gp = Wt + (size_t)n * 1152 + p * 128 + half * 64;
            #pragma unroll
            for (int q = 0; q < 8; ++q)
                *(bf16x8*)&Bs[n][half * 64 + q * 8] = *(const bf16x8*)(gp + q * 8);
        }

        if (p > 0) {
            int r = p - 1;
            int s0 = r * N_NODES + row0;
            #pragma unroll
            for (int rep = 0; rep < 2; ++rep) {
                int d = d0 + rep * 32;
                int beg = 0, end = 0;
                float iv = 0.f;
                if (d < nval) {
                    beg = offsets[s0 + d];
                    end = offsets[s0 + d + 1];
                    int c = end - beg;
                    iv = (c > 0) ? 1.0f / (float)c : 0.f;
                }
                float a[16];
                #pragma unroll
                for (int j = 0; j < 16; ++j) a[j] = 0.f;
                for (int i = beg; i < end; ++i) {
                    int src = sorted_src[i];
                    const uint4* hp = (const uint4*)(hb + (size_t)src * DIM + g * 16);
                    uint4 v0 = hp[0];
                    uint4 v1 = hp[1];
                    a[0]  += blo(v0.x); a[1]  += bhi(v0.x);
                    a[2]  += blo(v0.y); a[3]  += bhi(v0.y);
                    a[4]  += blo(v0.z); a[5]  += bhi(v0.z);
                    a[6]  += blo(v0.w); a[7]  += bhi(v0.w);
                    a[8]  += blo(v1.x); a[9]  += bhi(v1.x);
                    a[10] += blo(v1.y); a[11] += bhi(v1.y);
                    a[12] += blo(v1.z); a[13] += bhi(v1.z);
                    a[14] += blo(v1.w); a[15] += bhi(v1.w);
                }
                bf16x8 o0, o1;
                #pragma unroll
                for (int j = 0; j < 8; ++j) o0[j] = (short)f2b(a[j] * iv);
                #pragma unroll
                for (int j = 0; j < 8; ++j) o1[j] = (short)f2b(a[8 + j] * iv);
                *(bf16x8*)&Af[d][g * 16]     = o0;
                *(bf16x8*)&Af[d][g * 16 + 8] = o1;
            }
        }
        __syncthreads();   // Af / Bs ready

        // ---- MFMA: 4 k-steps of 32 ----
        #pragma unroll
        for (int kk = 0; kk < 4; ++kk) {
            bf16x8 afr[2], bfr[4];
            #pragma unroll
            for (int i = 0; i < 2; ++i) {
                int arow = wm * 32 + i * 16 + l16;
                if (p == 0) {
                    int grow = row0 + arow;
                    if (grow >= N_NODES) grow = N_NODES - 1;
                    afr[i] = *(const bf16x8*)(hb + (size_t)grow * DIM + kk * 32 + quad * 8);
                } else {
                    afr[i] = *(const bf16x8*)&Af[arow][kk * 32 + quad * 8];
                }
            }
            #pragma unroll
            for (int j = 0; j < 4; ++j)
                bfr[j] = *(const bf16x8*)&Bs[wn * 64 + j * 16 + l16][kk * 32 + quad * 8];
            #pragma unroll
            for (int i = 0; i < 2; ++i)
                #pragma unroll
                for (int j = 0; j < 4; ++j)
                    acc[i][j] = __builtin_amdgcn_mfma_f32_16x16x32_bf16(
                        afr[i], bfr[j], acc[i][j], 0, 0, 0);
        }
    }

    // epilogue: C/D layout col=lane&15, row=(lane>>4)*4+reg
    #pragma unroll
    for (int i = 0; i < 2; ++i) {
        int gr0 = row0 + wm * 32 + i * 16 + quad * 4;
        #pragma unroll
        for (int j = 0; j < 4; ++j) {
            int gc = wn * 64 + j * 16 + l16;
            float bv = bias[gc];
            #pragma unroll
            for (int r = 0; r < 4; ++r) {
                int grow = gr0 + r;
                if (grow < N_NODES) {
                    float v = acc[i][j][r] + bv;
                    hout[(size_t)grow * 128 + gc] = f2b(fmaxf(v, 0.f));
                }
            }
        }
    }
}

// ---------------------------------------------------------------------------
// score: out[t] = sum_d h[head,d]*rel_emb[rel,d]*h[tail,d]  (h in bf16)
__global__ void score_kernel(const unsigned short* __restrict__ hb,
                             const float* __restrict__ rel_emb,
                             const int* __restrict__ head,
                             const int* __restrict__ rel,
                             const int* __restrict__ tail,
                             float* __restrict__ out) {
    int t = blockIdx.x * 4 + (threadIdx.x >> 6);
    if (t >= N_TRIP) return;
    int lane = threadIdx.x & 63;
    unsigned int ph = ((const unsigned int*)(hb + (size_t)head[t] * DIM))[lane];
    unsigned int pt = ((const unsigned int*)(hb + (size_t)tail[t] * DIM))[lane];
    float2 rr = ((const float2*)(rel_emb + (size_t)rel[t] * DIM))[lane];
    float s = blo(ph) * rr.x * blo(pt) + bhi(ph) * rr.y * bhi(pt);
    #pragma unroll
    for (int off = 32; off; off >>= 1) s += __shfl_xor(s, off, 64);
    if (lane == 0) out[t] = s;
}

// ---------------------------------------------------------------------------
extern "C" void kernel_launch(void* const* d_in, const int* in_sizes, int n_in,
                              void* d_out, int out_size, void* d_ws, size_t ws_size,
                              hipStream_t stream) {
    const float* emb     = (const float*)d_in[0];
    const float* W0      = (const float*)d_in[1];
    const float* root0   = (const float*)d_in[2];
    const float* b0      = (const float*)d_in[3];
    const float* W1      = (const float*)d_in[4];
    const float* root1   = (const float*)d_in[5];
    const float* b1      = (const float*)d_in[6];
    const float* rel_emb = (const float*)d_in[7];
    const int* edge_index = (const int*)d_in[8];
    const int* edge_type  = (const int*)d_in[9];
    const int* head_idx   = (const int*)d_in[10];
    const int* rel_idx    = (const int*)d_in[11];
    const int* tail_idx   = (const int*)d_in[12];
    float* out = (float*)d_out;

    // workspace layout (~47 MB, all disjoint):
    char* p = (char*)d_ws;
    size_t hb_bytes = (size_t)N_NODES * DIM * sizeof(unsigned short);   // 12.8 MB
    size_t wt_bytes = (size_t)128 * 1152 * sizeof(unsigned short);      // 288 KB
    unsigned short* embb = (unsigned short*)p; p += hb_bytes;
    unsigned short* h1b  = (unsigned short*)p; p += hb_bytes;
    unsigned short* h2b  = (unsigned short*)p; p += hb_bytes;
    unsigned short* Wt0  = (unsigned short*)p; p += wt_bytes;
    unsigned short* Wt1  = (unsigned short*)p; p += wt_bytes;
    int* offsets = (int*)p;          p += (size_t)(NSEG + 1) * sizeof(int);
    int* sorted_src = (int*)p;       p += (size_t)N_EDGES * sizeof(int);
    int* cnt     = (int*)p;          p += (size_t)NSEG * sizeof(int);
    int* cursor  = (int*)p;          p += (size_t)NSEG * sizeof(int);
    int* blocksums = (int*)p;
    (void)ws_size; (void)in_sizes; (void)n_in; (void)out_size;

    dim3 blk256(256);

    // ---- sort edges by (rel, dst) segment (layer-invariant) ----
    hipMemsetAsync(cnt, 0, (size_t)NSEG * sizeof(int), stream);
    hist_kernel<<<(N_EDGES + 255) / 256, blk256, 0, stream>>>(edge_index, edge_type, cnt);
    scan1_kernel<<<N_SCAN_BLOCKS, blk256, 0, stream>>>(cnt, offsets, blocksums);
    scan2_kernel<<<1, 512, 0, stream>>>(blocksums);
    scan3_kernel<<<N_SCAN_BLOCKS, blk256, 0, stream>>>(offsets, blocksums, cursor);
    reorder_kernel<<<(N_EDGES + 255) / 256, blk256, 0, stream>>>(edge_index, edge_type,
                                                                 cursor, sorted_src);

    // ---- precision conversions ----
    cvt_emb_kernel<<<(N_NODES * DIM / 2 + 255) / 256, blk256, 0, stream>>>(emb, embb);
    cvt_w_kernel<<<128, blk256, 0, stream>>>(root0, W0, Wt0);
    cvt_w_kernel<<<128, blk256, 0, stream>>>(root1, W1, Wt1);

    int gemm_grid = (N_NODES + 63) / 64;           // 782

    // ---- fused layers ----
    fused_layer<<<gemm_grid, blk256, 0, stream>>>(embb, Wt0, b0, offsets, sorted_src, h1b);
    fused_layer<<<gemm_grid, blk256, 0, stream>>>(h1b, Wt1, b1, offsets, sorted_src, h2b);

    // ---- score ----
    score_kernel<<<(N_TRIP + 3) / 4, blk256, 0, stream>>>(h2b, rel_emb, head_idx, rel_idx,
                                                          tail_idx, out);
}

// Round 7
// 397.113 us; speedup vs baseline: 4.2216x; 1.3368x over previous
//
#include <hip/hip_runtime.h>
#include <hip/hip_bf16.h>

// Problem constants (from reference)
#define N_NODES 50000
#define N_REL   8
#define DIM     128      // IN_DIM == HID == 128
#define N_EDGES 800000
#define N_TRIP  100000
#define NSEG    (N_NODES * N_REL)   // 400000
#define SCAN_CHUNK 1024
#define N_SCAN_BLOCKS ((NSEG + SCAN_CHUNK - 1) / SCAN_CHUNK)  // 391

typedef __attribute__((ext_vector_type(8))) short bf16x8;
typedef __attribute__((ext_vector_type(4))) float f32x4;

static __device__ __forceinline__ unsigned short f2b(float f) {
    __hip_bfloat16 h = __float2bfloat16(f);
    return *reinterpret_cast<unsigned short*>(&h);
}
static __device__ __forceinline__ float blo(unsigned int u) {
    return __uint_as_float(u << 16);
}
static __device__ __forceinline__ float bhi(unsigned int u) {
    return __uint_as_float(u & 0xffff0000u);
}
// XOR-swizzled LDS offset (units: shorts). row-major 16 chunks of 16B per row,
// chunk c of row n lives at chunk slot (c ^ (n & 7)) -> conflict-free b128
// staging stores AND even-distribution frag reads.
static __device__ __forceinline__ int lds_off(int row, int chunk) {
    return (row * 16 + (chunk ^ (row & 7))) * 8;
}

// ---------------------------------------------------------------------------
// histogram over segments seg = dst*8 + rel   (dst-major)
__global__ void hist_kernel(const int* __restrict__ edge_index,
                            const int* __restrict__ edge_type,
                            int* __restrict__ cnt) {
    int e = blockIdx.x * blockDim.x + threadIdx.x;
    if (e >= N_EDGES) return;
    int dst = edge_index[N_EDGES + e];
    int r = edge_type[e];
    atomicAdd(&cnt[dst * N_REL + r], 1);
}

// ---------------------------------------------------------------------------
__global__ void scan1_kernel(const int* __restrict__ cnt,
                             int* __restrict__ offsets,
                             int* __restrict__ blocksums) {
    __shared__ int sh[256];
    int t = threadIdx.x;
    int base = blockIdx.x * SCAN_CHUNK + t * 4;
    int v[4];
    int s = 0;
    #pragma unroll
    for (int j = 0; j < 4; ++j) {
        v[j] = (base + j < NSEG) ? cnt[base + j] : 0;
        s += v[j];
    }
    sh[t] = s;
    __syncthreads();
    #pragma unroll
    for (int off = 1; off < 256; off <<= 1) {
        int x = (t >= off) ? sh[t - off] : 0;
        __syncthreads();
        sh[t] += x;
        __syncthreads();
    }
    int ex = sh[t] - s;
    #pragma unroll
    for (int j = 0; j < 4; ++j) {
        if (base + j < NSEG) offsets[base + j] = ex;
        ex += v[j];
    }
    if (t == 255) blocksums[blockIdx.x] = sh[255];
}

__global__ void scan2_kernel(int* __restrict__ blocksums) {
    __shared__ int sh[512];
    int t = threadIdx.x;
    int orig = (t < N_SCAN_BLOCKS) ? blocksums[t] : 0;
    sh[t] = orig;
    __syncthreads();
    #pragma unroll
    for (int off = 1; off < 512; off <<= 1) {
        int x = (t >= off) ? sh[t - off] : 0;
        __syncthreads();
        sh[t] += x;
        __syncthreads();
    }
    if (t < N_SCAN_BLOCKS) blocksums[t] = sh[t] - orig;
}

__global__ void scan3_kernel(int* __restrict__ offsets,
                             const int* __restrict__ blocksums,
                             int* __restrict__ cursor) {
    int t = threadIdx.x;
    int boff = blocksums[blockIdx.x];
    int base = blockIdx.x * SCAN_CHUNK + t * 4;
    #pragma unroll
    for (int j = 0; j < 4; ++j) {
        int i = base + j;
        if (i < NSEG) {
            int v = offsets[i] + boff;
            offsets[i] = v;
            cursor[i] = v;
        }
    }
    if (blockIdx.x == 0 && t == 0) offsets[NSEG] = N_EDGES;
}

// ---------------------------------------------------------------------------
// invcnt[i] = 1/max(offsets[i+1]-offsets[i], 1)
__global__ void invcnt_kernel(const int* __restrict__ offsets,
                              float* __restrict__ invcnt) {
    int i = blockIdx.x * blockDim.x + threadIdx.x;
    if (i >= NSEG) return;
    int c = offsets[i + 1] - offsets[i];
    invcnt[i] = (c > 0) ? 1.0f / (float)c : 0.f;
}

// ---------------------------------------------------------------------------
// reorder: sorted_pack[pos] = src | (rel<<16)
__global__ void reorder_kernel(const int* __restrict__ edge_index,
                               const int* __restrict__ edge_type,
                               int* __restrict__ cursor,
                               unsigned int* __restrict__ sorted_pack) {
    int e = blockIdx.x * blockDim.x + threadIdx.x;
    if (e >= N_EDGES) return;
    int src = edge_index[e];
    int dst = edge_index[N_EDGES + e];
    int r = edge_type[e];
    int seg = dst * N_REL + r;
    int pos = atomicAdd(&cursor[seg], 1);
    sorted_pack[pos] = (unsigned int)src | ((unsigned int)r << 16);
}

// ---------------------------------------------------------------------------
// cvt_emb: fp32 -> bf16, 2 elems/thread (packed)
__global__ void cvt_emb_kernel(const float* __restrict__ src,
                               unsigned short* __restrict__ dst) {
    int i = blockIdx.x * blockDim.x + threadIdx.x;
    const int npair = N_NODES * DIM / 2;
    if (i >= npair) return;
    float2 v = ((const float2*)src)[i];
    unsigned int p = (unsigned int)f2b(v.x) | ((unsigned int)f2b(v.y) << 16);
    ((unsigned int*)dst)[i] = p;
}

// ---------------------------------------------------------------------------
// cvt_w2: Wt2[s][n][k] bf16, s=0 -> root, s>=1 -> W_{s-1}; inputs [k][n] fp32.
__global__ void cvt_w2_kernel(const float* __restrict__ root,
                              const float* __restrict__ W,
                              unsigned short* __restrict__ Wt2) {
    int s = blockIdx.x;        // 0..8
    int n = blockIdx.y;        // 0..127
    int k = threadIdx.x;       // 0..127
    float v = (s == 0) ? root[k * 128 + n]
                       : W[((size_t)(s - 1) * 128 + k) * 128 + n];
    Wt2[((size_t)s * 128 + n) * 128 + k] = f2b(v);
}

// ---------------------------------------------------------------------------
// gemm9: Y[n, s, :] = h[n] @ B_s   (no bias/relu here)
// Grid (9, 782): blockIdx.x = slot s, blockIdx.y = 64-row M-tile.
// BM=64, BN=128, K=128 single pass. 4 waves, each 32x64 quadrant (2x4 frags).
__global__ __launch_bounds__(256) void gemm9(
        const unsigned short* __restrict__ hb,    // N x 128 bf16
        const unsigned short* __restrict__ Wt2,   // 9 x 128(n) x 128(k) bf16
        unsigned short* __restrict__ Y) {         // N x 9 x 128 bf16
    __shared__ unsigned short As[64 * 16 * 8];    // 64 rows x 16 chunks (16 KB)
    __shared__ unsigned short Bs[128 * 16 * 8];   // 128 rows x 16 chunks (32 KB)

    int tid = threadIdx.x;
    int wave = tid >> 6, lane = tid & 63;
    int wm = wave & 1, wn = wave >> 1;
    int quad = lane >> 4, l16 = lane & 15;
    int s = blockIdx.x;
    int row0 = blockIdx.y * 64;

    // ---- stage A: thread -> row tid>>2, chunks (tid&3)*4 .. +3 ----
    {
        int r = tid >> 2, c0 = (tid & 3) * 4;
        int grow = row0 + r;
        if (grow >= N_NODES) grow = N_NODES - 1;
        const unsigned short* gp = hb + (size_t)grow * DIM + c0 * 8;
        #pragma unroll
        for (int q = 0; q < 4; ++q)
            *(bf16x8*)&As[lds_off(r, c0 + q)] = *(const bf16x8*)(gp + q * 8);
    }
    // ---- stage B: thread -> row tid>>1, chunks (tid&1)*8 .. +7 ----
    {
        int n = tid >> 1, c0 = (tid & 1) * 8;
        const unsigned short* gp = Wt2 + ((size_t)s * 128 + n) * 128 + c0 * 8;
        #pragma unroll
        for (int q = 0; q < 8; ++q)
            *(bf16x8*)&Bs[lds_off(n, c0 + q)] = *(const bf16x8*)(gp + q * 8);
    }
    __syncthreads();

    f32x4 acc[2][4];
    #pragma unroll
    for (int i = 0; i < 2; ++i)
        #pragma unroll
        for (int j = 0; j < 4; ++j) acc[i][j] = (f32x4){0.f, 0.f, 0.f, 0.f};

    #pragma unroll
    for (int kk = 0; kk < 4; ++kk) {
        int chunk = kk * 4 + quad;
        bf16x8 afr[2], bfr[4];
        #pragma unroll
        for (int i = 0; i < 2; ++i)
            afr[i] = *(const bf16x8*)&As[lds_off(wm * 32 + i * 16 + l16, chunk)];
        #pragma unroll
        for (int j = 0; j < 4; ++j)
            bfr[j] = *(const bf16x8*)&Bs[lds_off(wn * 64 + j * 16 + l16, chunk)];
        #pragma unroll
        for (int i = 0; i < 2; ++i)
            #pragma unroll
            for (int j = 0; j < 4; ++j)
                acc[i][j] = __builtin_amdgcn_mfma_f32_16x16x32_bf16(
                    afr[i], bfr[j], acc[i][j], 0, 0, 0);
    }

    // epilogue: C/D layout col=lane&15, row=(lane>>4)*4+reg
    #pragma unroll
    for (int i = 0; i < 2; ++i) {
        int gr0 = row0 + wm * 32 + i * 16 + quad * 4;
        #pragma unroll
        for (int j = 0; j < 4; ++j) {
            int gc = wn * 64 + j * 16 + l16;
            #pragma unroll
            for (int r = 0; r < 4; ++r) {
                int grow = gr0 + r;
                if (grow < N_NODES)
                    Y[((size_t)grow * 9 + s) * 128 + gc] = f2b(acc[i][j][r]);
            }
        }
    }
}

// ---------------------------------------------------------------------------
// aggregate_out: one wave per dst.
// hout[dst,:] = relu(bias + Y[dst,0,:] + sum_e inv[dst,rel_e] * Y[src_e,1+rel_e,:])
__global__ __launch_bounds__(256) void aggregate_out(
        const unsigned short* __restrict__ Y,        // N x 9 x 128 bf16
        const float* __restrict__ bias,              // 128
        const int* __restrict__ offsets,             // NSEG+1 (dst-major)
        const unsigned int* __restrict__ sorted_pack,// N_EDGES: src | rel<<16
        const float* __restrict__ invcnt,            // NSEG
        unsigned short* __restrict__ hout) {         // N x 128 bf16
    int dst = blockIdx.x * 4 + (threadIdx.x >> 6);
    if (dst >= N_NODES) return;
    int lane = threadIdx.x & 63;
    const unsigned int* Yu = (const unsigned int*)Y;

    // root slot
    unsigned int r0 = Yu[(size_t)dst * 9 * 64 + lane];
    float a0 = blo(r0), a1 = bhi(r0);

    int beg = offsets[dst * N_REL];
    int end = offsets[dst * N_REL + N_REL];
    for (int base = beg; base < end; base += 64) {
        int np = end - base; if (np > 64) np = 64;
        unsigned int pk = 0; float ivl = 0.f;
        if (lane < np) {
            pk = sorted_pack[base + lane];
            ivl = invcnt[dst * N_REL + (int)(pk >> 16)];
        }
        int j = 0;
        for (; j + 3 < np; j += 4) {
            unsigned int p0 = __shfl((int)pk, j, 64);
            unsigned int p1 = __shfl((int)pk, j + 1, 64);
            unsigned int p2 = __shfl((int)pk, j + 2, 64);
            unsigned int p3 = __shfl((int)pk, j + 3, 64);
            float i0 = __shfl(ivl, j, 64);
            float i1 = __shfl(ivl, j + 1, 64);
            float i2 = __shfl(ivl, j + 2, 64);
            float i3 = __shfl(ivl, j + 3, 64);
            unsigned int v0 = Yu[((size_t)(p0 & 0xffffu) * 9 + 1 + (p0 >> 16)) * 64 + lane];
            unsigned int v1 = Yu[((size_t)(p1 & 0xffffu) * 9 + 1 + (p1 >> 16)) * 64 + lane];
            unsigned int v2 = Yu[((size_t)(p2 & 0xffffu) * 9 + 1 + (p2 >> 16)) * 64 + lane];
            unsigned int v3 = Yu[((size_t)(p3 & 0xffffu) * 9 + 1 + (p3 >> 16)) * 64 + lane];
            a0 = fmaf(blo(v0), i0, a0); a1 = fmaf(bhi(v0), i0, a1);
            a0 = fmaf(blo(v1), i1, a0); a1 = fmaf(bhi(v1), i1, a1);
            a0 = fmaf(blo(v2), i2, a0); a1 = fmaf(bhi(v2), i2, a1);
            a0 = fmaf(blo(v3), i3, a0); a1 = fmaf(bhi(v3), i3, a1);
        }
        for (; j < np; ++j) {
            unsigned int pj = __shfl((int)pk, j, 64);
            float ij = __shfl(ivl, j, 64);
            unsigned int v = Yu[((size_t)(pj & 0xffffu) * 9 + 1 + (pj >> 16)) * 64 + lane];
            a0 = fmaf(blo(v), ij, a0); a1 = fmaf(bhi(v), ij, a1);
        }
    }
    float2 bv = ((const float2*)bias)[lane];
    a0 = fmaxf(a0 + bv.x, 0.f);
    a1 = fmaxf(a1 + bv.y, 0.f);
    unsigned int po = (unsigned int)f2b(a0) | ((unsigned int)f2b(a1) << 16);
    ((unsigned int*)(hout + (size_t)dst * DIM))[lane] = po;
}

// ---------------------------------------------------------------------------
// score: out[t] = sum_d h[head,d]*rel_emb[rel,d]*h[tail,d]  (h in bf16)
__global__ void score_kernel(const unsigned short* __restrict__ hb,
                             const float* __restrict__ rel_emb,
                             const int* __restrict__ head,
                             const int* __restrict__ rel,
                             const int* __restrict__ tail,
                             float* __restrict__ out) {
    int t = blockIdx.x * 4 + (threadIdx.x >> 6);
    if (t >= N_TRIP) return;
    int lane = threadIdx.x & 63;
    unsigned int ph = ((const unsigned int*)(hb + (size_t)head[t] * DIM))[lane];
    unsigned int pt = ((const unsigned int*)(hb + (size_t)tail[t] * DIM))[lane];
    float2 rr = ((const float2*)(rel_emb + (size_t)rel[t] * DIM))[lane];
    float s = blo(ph) * rr.x * blo(pt) + bhi(ph) * rr.y * bhi(pt);
    #pragma unroll
    for (int off = 32; off; off >>= 1) s += __shfl_xor(s, off, 64);
    if (lane == 0) out[t] = s;
}

// ---------------------------------------------------------------------------
extern "C" void kernel_launch(void* const* d_in, const int* in_sizes, int n_in,
                              void* d_out, int out_size, void* d_ws, size_t ws_size,
                              hipStream_t stream) {
    const float* emb     = (const float*)d_in[0];
    const float* W0      = (const float*)d_in[1];
    const float* root0   = (const float*)d_in[2];
    const float* b0      = (const float*)d_in[3];
    const float* W1      = (const float*)d_in[4];
    const float* root1   = (const float*)d_in[5];
    const float* b1      = (const float*)d_in[6];
    const float* rel_emb = (const float*)d_in[7];
    const int* edge_index = (const int*)d_in[8];
    const int* edge_type  = (const int*)d_in[9];
    const int* head_idx   = (const int*)d_in[10];
    const int* rel_idx    = (const int*)d_in[11];
    const int* tail_idx   = (const int*)d_in[12];
    float* out = (float*)d_out;

    // workspace layout (~165 MB, all disjoint):
    char* p = (char*)d_ws;
    size_t y_bytes   = (size_t)N_NODES * 9 * DIM * sizeof(unsigned short); // 115.2 MB
    size_t hb_bytes  = (size_t)N_NODES * DIM * sizeof(unsigned short);     // 12.8 MB
    size_t wt2_bytes = (size_t)9 * 128 * 128 * sizeof(unsigned short);     // 294912 B
    unsigned short* Y    = (unsigned short*)p; p += y_bytes;
    unsigned short* embb = (unsigned short*)p; p += hb_bytes;
    unsigned short* h1b  = (unsigned short*)p; p += hb_bytes;
    unsigned short* h2b  = (unsigned short*)p; p += hb_bytes;
    unsigned short* Wt2a = (unsigned short*)p; p += wt2_bytes;
    unsigned short* Wt2b = (unsigned short*)p; p += wt2_bytes;
    int* offsets = (int*)p;           p += (size_t)(NSEG + 1) * sizeof(int);
    float* invcnt = (float*)p;        p += (size_t)NSEG * sizeof(float);
    unsigned int* sorted_pack = (unsigned int*)p; p += (size_t)N_EDGES * sizeof(unsigned int);
    int* cnt     = (int*)p;           p += (size_t)NSEG * sizeof(int);
    int* cursor  = (int*)p;           p += (size_t)NSEG * sizeof(int);
    int* blocksums = (int*)p;
    (void)ws_size; (void)in_sizes; (void)n_in; (void)out_size;

    dim3 blk256(256);

    // ---- sort edges by (dst, rel) segment, dst-major (layer-invariant) ----
    hipMemsetAsync(cnt, 0, (size_t)NSEG * sizeof(int), stream);
    hist_kernel<<<(N_EDGES + 255) / 256, blk256, 0, stream>>>(edge_index, edge_type, cnt);
    scan1_kernel<<<N_SCAN_BLOCKS, blk256, 0, stream>>>(cnt, offsets, blocksums);
    scan2_kernel<<<1, 512, 0, stream>>>(blocksums);
    scan3_kernel<<<N_SCAN_BLOCKS, blk256, 0, stream>>>(offsets, blocksums, cursor);
    invcnt_kernel<<<(NSEG + 255) / 256, blk256, 0, stream>>>(offsets, invcnt);
    reorder_kernel<<<(N_EDGES + 255) / 256, blk256, 0, stream>>>(edge_index, edge_type,
                                                                 cursor, sorted_pack);

    // ---- precision conversions ----
    cvt_emb_kernel<<<(N_NODES * DIM / 2 + 255) / 256, blk256, 0, stream>>>(emb, embb);
    cvt_w2_kernel<<<dim3(9, 128), 128, 0, stream>>>(root0, W0, Wt2a);
    cvt_w2_kernel<<<dim3(9, 128), 128, 0, stream>>>(root1, W1, Wt2b);

    dim3 ggrid(9, (N_NODES + 63) / 64);            // 9 x 782
    int agrid = (N_NODES + 3) / 4;                 // 12500

    // ---- layer 0: transform then aggregate ----
    gemm9<<<ggrid, blk256, 0, stream>>>(embb, Wt2a, Y);
    aggregate_out<<<agrid, blk256, 0, stream>>>(Y, b0, offsets, sorted_pack, invcnt, h1b);

    // ---- layer 1 ----
    gemm9<<<ggrid, blk256, 0, stream>>>(h1b, Wt2b, Y);
    aggregate_out<<<agrid, blk256, 0, stream>>>(Y, b1, offsets, sorted_pack, invcnt, h2b);

    // ---- score ----
    score_kernel<<<(N_TRIP + 3) / 4, blk256, 0, stream>>>(h2b, rel_emb, head_idx, rel_idx,
                                                          tail_idx, out);
}

// Round 8
// 339.648 us; speedup vs baseline: 4.9359x; 1.1692x over previous
//
#include <hip/hip_runtime.h>
#include <hip/hip_bf16.h>

// Problem constants (from reference)
#define N_NODES 50000
#define N_REL   8
#define DIM     128      // IN_DIM == HID == 128
#define N_EDGES 800000
#define N_TRIP  100000
#define NSEG    (N_NODES * N_REL)   // 400000
#define NBUCKET 196                 // ceil(50000/256) dst buckets
#define CAP     6144                // slack slots per bucket (mean 4082, +32 sigma)

typedef __attribute__((ext_vector_type(8))) short bf16x8;
typedef __attribute__((ext_vector_type(4))) float f32x4;

static __device__ __forceinline__ unsigned short f2b(float f) {
    __hip_bfloat16 h = __float2bfloat16(f);
    return *reinterpret_cast<unsigned short*>(&h);
}
static __device__ __forceinline__ float blo(unsigned int u) {
    return __uint_as_float(u << 16);
}
static __device__ __forceinline__ float bhi(unsigned int u) {
    return __uint_as_float(u & 0xffff0000u);
}
// XOR-swizzled LDS offset (units: shorts): chunk c of row n -> slot (c ^ (n&7))
static __device__ __forceinline__ int lds_off(int row, int chunk) {
    return (row * 16 + (chunk ^ (row & 7))) * 8;
}

// ---------------------------------------------------------------------------
// bucket_scatter: bin edges by dst>>8 into fixed-capacity slack regions.
// packed word: src[0:16) | rel[16:19) | dstLow[19:27)
__global__ __launch_bounds__(256) void bucket_scatter(
        const int* __restrict__ edge_index,
        const int* __restrict__ edge_type,
        int* __restrict__ gcnt,
        unsigned int* __restrict__ slack) {
    __shared__ int hist[NBUCKET];
    __shared__ int cur[NBUCKET];
    int tid = threadIdx.x;
    for (int i = tid; i < NBUCKET; i += 256) hist[i] = 0;
    __syncthreads();
    int base = blockIdx.x * 4096;
    unsigned int w[16];
    int bk[16];
    #pragma unroll
    for (int i = 0; i < 16; ++i) {
        int e = base + i * 256 + tid;
        if (e < N_EDGES) {
            int src = edge_index[e];
            int dst = edge_index[N_EDGES + e];
            int r = edge_type[e];
            w[i] = (unsigned int)src | ((unsigned int)r << 16) |
                   ((unsigned int)(dst & 255) << 19);
            bk[i] = dst >> 8;
            atomicAdd(&hist[bk[i]], 1);
        } else {
            bk[i] = -1;
        }
    }
    __syncthreads();
    for (int i = tid; i < NBUCKET; i += 256)
        cur[i] = atomicAdd(&gcnt[i], hist[i]);
    __syncthreads();
    #pragma unroll
    for (int i = 0; i < 16; ++i) {
        if (bk[i] >= 0) {
            int p = atomicAdd(&cur[bk[i]], 1);
            if (p < CAP) slack[(size_t)bk[i] * CAP + p] = w[i];
        }
    }
}

// ---------------------------------------------------------------------------
// bucket_scan: exclusive scan of 196 bucket counts; also set sentinel.
__global__ void bucket_scan(const int* __restrict__ gcnt,
                            int* __restrict__ gbase,
                            int* __restrict__ offsets) {
    __shared__ int sh[256];
    int t = threadIdx.x;
    int v = (t < NBUCKET) ? gcnt[t] : 0;
    sh[t] = v;
    __syncthreads();
    #pragma unroll
    for (int off = 1; off < 256; off <<= 1) {
        int x = (t >= off) ? sh[t - off] : 0;
        __syncthreads();
        sh[t] += x;
        __syncthreads();
    }
    if (t < NBUCKET) gbase[t] = sh[t] - v;
    if (t == 0) offsets[NSEG] = N_EDGES;
}

// ---------------------------------------------------------------------------
// bucket_sort: one block per bucket. LDS counting sort over 2048 local segs
// (dstLow*8+rel). Writes sorted_pack (src|rel<<16) and offsets, coalesced.
__global__ __launch_bounds__(256) void bucket_sort(
        const unsigned int* __restrict__ slack,
        const int* __restrict__ gcnt,
        const int* __restrict__ gbase,
        unsigned int* __restrict__ sorted_pack,
        int* __restrict__ offsets) {
    __shared__ unsigned int ebuf[CAP];   // 24 KB
    __shared__ unsigned int obuf[CAP];   // 24 KB
    __shared__ int hist[2048];           // 8 KB (later reused as cursor)
    __shared__ int excl[2048];           // 8 KB
    __shared__ int sh[256];
    int b = blockIdx.x, t = threadIdx.x;
    int n = gcnt[b]; if (n > CAP) n = CAP;
    int bb = gbase[b];
    for (int i = t; i < n; i += 256) ebuf[i] = slack[(size_t)b * CAP + i];
    for (int i = t; i < 2048; i += 256) hist[i] = 0;
    __syncthreads();
    for (int i = t; i < n; i += 256) {
        unsigned int w = ebuf[i];
        int seg = (int)((w >> 19) << 3) | (int)((w >> 16) & 7u);
        atomicAdd(&hist[seg], 1);
    }
    __syncthreads();
    // blocked exclusive scan over 2048: thread t owns [t*8, t*8+8)
    int c[8];
    int s = 0;
    #pragma unroll
    for (int j = 0; j < 8; ++j) { c[j] = hist[t * 8 + j]; s += c[j]; }
    sh[t] = s;
    __syncthreads();
    #pragma unroll
    for (int off = 1; off < 256; off <<= 1) {
        int x = (t >= off) ? sh[t - off] : 0;
        __syncthreads();
        sh[t] += x;
        __syncthreads();
    }
    int ex = sh[t] - s;
    #pragma unroll
    for (int j = 0; j < 8; ++j) { excl[t * 8 + j] = ex; ex += c[j]; }
    __syncthreads();
    #pragma unroll
    for (int j = 0; j < 8; ++j) hist[t * 8 + j] = excl[t * 8 + j];  // cursor
    __syncthreads();
    for (int i = t; i < n; i += 256) {
        unsigned int w = ebuf[i];
        int seg = (int)((w >> 19) << 3) | (int)((w >> 16) & 7u);
        int p = atomicAdd(&hist[seg], 1);
        obuf[p] = w & 0x7ffffu;          // src | rel<<16
    }
    __syncthreads();
    for (int i = t; i < n; i += 256) sorted_pack[bb + i] = obuf[i];
    int segbase = b * 2048;
    for (int j = t; j < 2048; j += 256) {
        int gseg = segbase + j;
        if (gseg < NSEG) offsets[gseg] = bb + excl[j];
    }
}

// ---------------------------------------------------------------------------
// invcnt[i] = 1/max(count, 1)
__global__ void invcnt_kernel(const int* __restrict__ offsets,
                              float* __restrict__ invcnt) {
    int i = blockIdx.x * blockDim.x + threadIdx.x;
    if (i >= NSEG) return;
    int c = offsets[i + 1] - offsets[i];
    invcnt[i] = (c > 0) ? 1.0f / (float)c : 0.f;
}

// ---------------------------------------------------------------------------
// cvt_emb: fp32 -> bf16, 2 elems/thread (packed)
__global__ void cvt_emb_kernel(const float* __restrict__ src,
                               unsigned short* __restrict__ dst) {
    int i = blockIdx.x * blockDim.x + threadIdx.x;
    const int npair = N_NODES * DIM / 2;
    if (i >= npair) return;
    float2 v = ((const float2*)src)[i];
    unsigned int p = (unsigned int)f2b(v.x) | ((unsigned int)f2b(v.y) << 16);
    ((unsigned int*)dst)[i] = p;
}

// ---------------------------------------------------------------------------
// cvt_w2: Wt2[s][n][k] bf16, s=0 -> root, s>=1 -> W_{s-1}; inputs [k][n] fp32.
__global__ void cvt_w2_kernel(const float* __restrict__ root,
                              const float* __restrict__ W,
                              unsigned short* __restrict__ Wt2) {
    int s = blockIdx.x;        // 0..8
    int n = blockIdx.y;        // 0..127
    int k = threadIdx.x;       // 0..127
    float v = (s == 0) ? root[k * 128 + n]
                       : W[((size_t)(s - 1) * 128 + k) * 128 + n];
    Wt2[((size_t)s * 128 + n) * 128 + k] = f2b(v);
}

// ---------------------------------------------------------------------------
// gemm9_all: Y[s][n][:] = h[n] @ B_s for s=0..8 (slot-major Y).
// One block per 64-row M-tile (782 blocks). A-frags held in registers for all
// 9 slots (loaded once from global); only B_s staged in LDS per slot.
__global__ __launch_bounds__(256) void gemm9_all(
        const unsigned short* __restrict__ hb,    // N x 128 bf16
        const unsigned short* __restrict__ Wt2,   // 9 x 128(n) x 128(k) bf16
        unsigned short* __restrict__ Y) {         // 9 x N x 128 bf16
    __shared__ unsigned short Bs[128 * 16 * 8];   // 32 KB swizzled

    int tid = threadIdx.x;
    int wave = tid >> 6, lane = tid & 63;
    int wm = wave & 1, wn = wave >> 1;
    int quad = lane >> 4, l16 = lane & 15;
    int row0 = blockIdx.x * 64;

    // ---- A fragments: direct global -> registers, once ----
    bf16x8 afr[2][4];
    #pragma unroll
    for (int i = 0; i < 2; ++i) {
        int grow = row0 + wm * 32 + i * 16 + l16;
        if (grow >= N_NODES) grow = N_NODES - 1;
        #pragma unroll
        for (int kk = 0; kk < 4; ++kk)
            afr[i][kk] = *(const bf16x8*)(hb + (size_t)grow * DIM + kk * 32 + quad * 8);
    }

    for (int s = 0; s < 9; ++s) {
        __syncthreads();   // previous slot's Bs reads done
        {
            int n = tid >> 1, c0 = (tid & 1) * 8;
            const unsigned short* gp = Wt2 + ((size_t)s * 128 + n) * 128 + c0 * 8;
            #pragma unroll
            for (int q = 0; q < 8; ++q)
                *(bf16x8*)&Bs[lds_off(n, c0 + q)] = *(const bf16x8*)(gp + q * 8);
        }
        __syncthreads();

        f32x4 acc[2][4];
        #pragma unroll
        for (int i = 0; i < 2; ++i)
            #pragma unroll
            for (int j = 0; j < 4; ++j) acc[i][j] = (f32x4){0.f, 0.f, 0.f, 0.f};

        #pragma unroll
        for (int kk = 0; kk < 4; ++kk) {
            int chunk = kk * 4 + quad;
            bf16x8 bfr[4];
            #pragma unroll
            for (int j = 0; j < 4; ++j)
                bfr[j] = *(const bf16x8*)&Bs[lds_off(wn * 64 + j * 16 + l16, chunk)];
            #pragma unroll
            for (int i = 0; i < 2; ++i)
                #pragma unroll
                for (int j = 0; j < 4; ++j)
                    acc[i][j] = __builtin_amdgcn_mfma_f32_16x16x32_bf16(
                        afr[i][kk], bfr[j], acc[i][j], 0, 0, 0);
        }

        // epilogue: C/D layout col=lane&15, row=(lane>>4)*4+reg
        #pragma unroll
        for (int i = 0; i < 2; ++i) {
            int gr0 = row0 + wm * 32 + i * 16 + quad * 4;
            #pragma unroll
            for (int j = 0; j < 4; ++j) {
                int gc = wn * 64 + j * 16 + l16;
                #pragma unroll
                for (int r = 0; r < 4; ++r) {
                    int grow = gr0 + r;
                    if (grow < N_NODES)
                        Y[((size_t)s * N_NODES + grow) * 128 + gc] = f2b(acc[i][j][r]);
                }
            }
        }
    }
}

// ---------------------------------------------------------------------------
// aggregate_out: one wave per dst.
// hout[dst,:] = relu(bias + Y[0][dst,:] + sum_e inv[dst,rel_e]*Y[1+rel_e][src_e,:])
__global__ __launch_bounds__(256) void aggregate_out(
        const unsigned short* __restrict__ Y,        // 9 x N x 128 bf16
        const float* __restrict__ bias,              // 128
        const int* __restrict__ offsets,             // NSEG+1 (dst-major)
        const unsigned int* __restrict__ sorted_pack,// N_EDGES: src | rel<<16
        const float* __restrict__ invcnt,            // NSEG
        unsigned short* __restrict__ hout) {         // N x 128 bf16
    int dst = blockIdx.x * 4 + (threadIdx.x >> 6);
    if (dst >= N_NODES) return;
    int lane = threadIdx.x & 63;
    const unsigned int* Yu = (const unsigned int*)Y;

    // root slot (s = 0)
    unsigned int r0 = Yu[(size_t)dst * 64 + lane];
    float a0 = blo(r0), a1 = bhi(r0);

    int beg = offsets[dst * N_REL];
    int end = offsets[dst * N_REL + N_REL];
    for (int base = beg; base < end; base += 64) {
        int np = end - base; if (np > 64) np = 64;
        unsigned int pk = 0; float ivl = 0.f;
        if (lane < np) {
            pk = sorted_pack[base + lane];
            ivl = invcnt[dst * N_REL + (int)(pk >> 16)];
        }
        int j = 0;
        for (; j + 3 < np; j += 4) {
            unsigned int p0 = __shfl((int)pk, j, 64);
            unsigned int p1 = __shfl((int)pk, j + 1, 64);
            unsigned int p2 = __shfl((int)pk, j + 2, 64);
            unsigned int p3 = __shfl((int)pk, j + 3, 64);
            float i0 = __shfl(ivl, j, 64);
            float i1 = __shfl(ivl, j + 1, 64);
            float i2 = __shfl(ivl, j + 2, 64);
            float i3 = __shfl(ivl, j + 3, 64);
            unsigned int v0 = Yu[((size_t)(1 + (p0 >> 16)) * N_NODES + (p0 & 0xffffu)) * 64 + lane];
            unsigned int v1 = Yu[((size_t)(1 + (p1 >> 16)) * N_NODES + (p1 & 0xffffu)) * 64 + lane];
            unsigned int v2 = Yu[((size_t)(1 + (p2 >> 16)) * N_NODES + (p2 & 0xffffu)) * 64 + lane];
            unsigned int v3 = Yu[((size_t)(1 + (p3 >> 16)) * N_NODES + (p3 & 0xffffu)) * 64 + lane];
            a0 = fmaf(blo(v0), i0, a0); a1 = fmaf(bhi(v0), i0, a1);
            a0 = fmaf(blo(v1), i1, a0); a1 = fmaf(bhi(v1), i1, a1);
            a0 = fmaf(blo(v2), i2, a0); a1 = fmaf(bhi(v2), i2, a1);
            a0 = fmaf(blo(v3), i3, a0); a1 = fmaf(bhi(v3), i3, a1);
        }
        for (; j < np; ++j) {
            unsigned int pj = __shfl((int)pk, j, 64);
            float ij = __shfl(ivl, j, 64);
            unsigned int v = Yu[((size_t)(1 + (pj >> 16)) * N_NODES + (pj & 0xffffu)) * 64 + lane];
            a0 = fmaf(blo(v), ij, a0); a1 = fmaf(bhi(v), ij, a1);
        }
    }
    float2 bv = ((const float2*)bias)[lane];
    a0 = fmaxf(a0 + bv.x, 0.f);
    a1 = fmaxf(a1 + bv.y, 0.f);
    unsigned int po = (unsigned int)f2b(a0) | ((unsigned int)f2b(a1) << 16);
    ((unsigned int*)(hout + (size_t)dst * DIM))[lane] = po;
}

// ---------------------------------------------------------------------------
// score: out[t] = sum_d h[head,d]*rel_emb[rel,d]*h[tail,d]  (h in bf16)
__global__ void score_kernel(const unsigned short* __restrict__ hb,
                             const float* __restrict__ rel_emb,
                             const int* __restrict__ head,
                             const int* __restrict__ rel,
                             const int* __restrict__ tail,
                             float* __restrict__ out) {
    int t = blockIdx.x * 4 + (threadIdx.x >> 6);
    if (t >= N_TRIP) return;
    int lane = threadIdx.x & 63;
    unsigned int ph = ((const unsigned int*)(hb + (size_t)head[t] * DIM))[lane];
    unsigned int pt = ((const unsigned int*)(hb + (size_t)tail[t] * DIM))[lane];
    float2 rr = ((const float2*)(rel_emb + (size_t)rel[t] * DIM))[lane];
    float s = blo(ph) * rr.x * blo(pt) + bhi(ph) * rr.y * bhi(pt);
    #pragma unroll
    for (int off = 32; off; off >>= 1) s += __shfl_xor(s, off, 64);
    if (lane == 0) out[t] = s;
}

// ---------------------------------------------------------------------------
extern "C" void kernel_launch(void* const* d_in, const int* in_sizes, int n_in,
                              void* d_out, int out_size, void* d_ws, size_t ws_size,
                              hipStream_t stream) {
    const float* emb     = (const float*)d_in[0];
    const float* W0      = (const float*)d_in[1];
    const float* root0   = (const float*)d_in[2];
    const float* b0      = (const float*)d_in[3];
    const float* W1      = (const float*)d_in[4];
    const float* root1   = (const float*)d_in[5];
    const float* b1      = (const float*)d_in[6];
    const float* rel_emb = (const float*)d_in[7];
    const int* edge_index = (const int*)d_in[8];
    const int* edge_type  = (const int*)d_in[9];
    const int* head_idx   = (const int*)d_in[10];
    const int* rel_idx    = (const int*)d_in[11];
    const int* tail_idx   = (const int*)d_in[12];
    float* out = (float*)d_out;

    // workspace layout (~166 MB, all disjoint):
    char* p = (char*)d_ws;
    size_t y_bytes   = (size_t)9 * N_NODES * DIM * sizeof(unsigned short); // 115.2 MB
    size_t hb_bytes  = (size_t)N_NODES * DIM * sizeof(unsigned short);     // 12.8 MB
    size_t wt2_bytes = (size_t)9 * 128 * 128 * sizeof(unsigned short);     // 294912 B
    unsigned short* Y    = (unsigned short*)p; p += y_bytes;
    unsigned short* embb = (unsigned short*)p; p += hb_bytes;
    unsigned short* h1b  = (unsigned short*)p; p += hb_bytes;
    unsigned short* h2b  = (unsigned short*)p; p += hb_bytes;
    unsigned short* Wt2a = (unsigned short*)p; p += wt2_bytes;
    unsigned short* Wt2b = (unsigned short*)p; p += wt2_bytes;
    int* offsets = (int*)p;           p += (size_t)(NSEG + 1) * sizeof(int);
    float* invcnt = (float*)p;        p += (size_t)NSEG * sizeof(float);
    unsigned int* sorted_pack = (unsigned int*)p; p += (size_t)N_EDGES * sizeof(unsigned int);
    unsigned int* slack = (unsigned int*)p; p += (size_t)NBUCKET * CAP * sizeof(unsigned int);
    int* gcnt  = (int*)p;             p += (size_t)NBUCKET * sizeof(int);
    int* gbase = (int*)p;
    (void)ws_size; (void)in_sizes; (void)n_in; (void)out_size;

    dim3 blk256(256);

    // ---- 2-pass bucket sort of edges by (dst, rel), dst-major ----
    hipMemsetAsync(gcnt, 0, (size_t)NBUCKET * sizeof(int), stream);
    bucket_scatter<<<(N_EDGES + 4095) / 4096, blk256, 0, stream>>>(edge_index, edge_type,
                                                                   gcnt, slack);
    bucket_scan<<<1, 256, 0, stream>>>(gcnt, gbase, offsets);
    bucket_sort<<<NBUCKET, blk256, 0, stream>>>(slack, gcnt, gbase, sorted_pack, offsets);
    invcnt_kernel<<<(NSEG + 255) / 256, blk256, 0, stream>>>(offsets, invcnt);

    // ---- precision conversions ----
    cvt_emb_kernel<<<(N_NODES * DIM / 2 + 255) / 256, blk256, 0, stream>>>(emb, embb);
    cvt_w2_kernel<<<dim3(9, 128), 128, 0, stream>>>(root0, W0, Wt2a);
    cvt_w2_kernel<<<dim3(9, 128), 128, 0, stream>>>(root1, W1, Wt2b);

    int ggrid = (N_NODES + 63) / 64;               // 782
    int agrid = (N_NODES + 3) / 4;                 // 12500

    // ---- layer 0: transform then aggregate ----
    gemm9_all<<<ggrid, blk256, 0, stream>>>(embb, Wt2a, Y);
    aggregate_out<<<agrid, blk256, 0, stream>>>(Y, b0, offsets, sorted_pack, invcnt, h1b);

    // ---- layer 1 ----
    gemm9_all<<<ggrid, blk256, 0, stream>>>(h1b, Wt2b, Y);
    aggregate_out<<<agrid, blk256, 0, stream>>>(Y, b1, offsets, sorted_pack, invcnt, h2b);

    // ---- score ----
    score_kernel<<<(N_TRIP + 3) / 4, blk256, 0, stream>>>(h2b, rel_emb, head_idx, rel_idx,
                                                          tail_idx, out);
}